// Round 4
// baseline (1532.347 us; speedup 1.0000x reference)
//
#include <hip/hip_runtime.h>
#include <hip/hip_bf16.h>
#include <math.h>

typedef unsigned short u16;
typedef unsigned int   u32;
typedef _Float16 f16x8 __attribute__((ext_vector_type(8)));
typedef float f32x4  __attribute__((ext_vector_type(4)));

#define Bb 32
#define Tt 2048
#define Ee 1024
#define Mm (Bb*Tt)

__device__ __forceinline__ float tanh_fast(float x) {
  float ax = fminf(fabsf(x), 15.0f);
  float e  = __expf(2.0f * ax);
  float t  = 1.0f - 2.0f / (e + 1.0f);
  return copysignf(t, x);
}

__device__ __forceinline__ u32 pack2h(float a, float b) {
  _Float16 ha = (_Float16)a, hb = (_Float16)b;   // v_cvt_f16_f32 (RTN) — numerics preserved
  return (u32)__builtin_bit_cast(u16, ha) | ((u32)__builtin_bit_cast(u16, hb) << 16);
}

// async global->LDS, 16B per lane; LDS dest is wave-uniform base + lane*16
__device__ __forceinline__ void glds16(const u16* g, u16* l) {
  __builtin_amdgcn_global_load_lds(
      (const __attribute__((address_space(1))) void*)g,
      (__attribute__((address_space(3))) void*)l, 16, 0, 0);
}

// ---------------- K0: W (K x N fp32) -> Wt_hi/Wt_lo (N x K fp16 split) ----------------
__global__ __launch_bounds__(256) void wt_convert(const float* __restrict__ W,
                                                  u16* __restrict__ Wt_hi,
                                                  u16* __restrict__ Wt_lo) {
  __shared__ float tile[32][33];
  int n0 = blockIdx.x * 32, k0 = blockIdx.y * 32;
  int tx = threadIdx.x, ty = threadIdx.y;   // 32 x 8
#pragma unroll
  for (int i = 0; i < 4; ++i)
    tile[ty + 8*i][tx] = W[(size_t)(k0 + ty + 8*i) * Ee + n0 + tx];
  __syncthreads();
#pragma unroll
  for (int i = 0; i < 4; ++i) {
    float v = tile[tx][ty + 8*i];
    _Float16 hi = (_Float16)v;
    float rem = v - (float)hi;
    _Float16 lo = (_Float16)rem;
    size_t idx = (size_t)(n0 + ty + 8*i) * Ee + k0 + tx;
    Wt_hi[idx] = __builtin_bit_cast(u16, hi);
    Wt_lo[idx] = __builtin_bit_cast(u16, lo);
  }
}

// ---------------- K1: ht = tanh(enc@W + b), fused score = ctx . ht ----------------
// 256x128 tile, BK=32, 4 waves x wave-tile 128x64. Round-4: revert to the
// round-2 skeleton (2 barriers/step; round-3's 8-barrier phase split regressed
// 378->530 with 4-wave blocks) plus two targeted fixes:
//  (1) de-paired hi/lo MFMAs: per j, issue 8x hi then 8x lo — each lo trails
//      its same-acc hi by 8 independent MFMAs (~40cyc > result latency), vs
//      the old adjacent pair which stalled ~12cyc x 32 pairs/step.
//      Per-accumulator add order unchanged (hi then lo per kt) -> bit-identical.
//  (2) A prefetched TWO K-steps ahead (avA/avB named reg sets, even/odd
//      unrolled body) — enc's ~900cyc HBM latency was ~300cyc exposed at the
//      tail pack with 1-step prefetch; now fully covered. B stays 1-deep
//      (Wt is 4MB, L2-resident).
// LDS: A 2x16KB + Bhi 2x8KB + Blo 2x8KB = 64KB -> 2 blocks/CU.
// 16B-chunk XOR swizzle (phys = logical ^ ((row>>1)&3)): measured 0 conflicts.
__global__ __launch_bounds__(256, 2) void gemm_tanh_score(
    const float* __restrict__ enc, const float* __restrict__ ctx,
    const float* __restrict__ bias,
    const u16* __restrict__ Wt_hi, const u16* __restrict__ Wt_lo,
    u16* __restrict__ ht, float* __restrict__ scores) {
  __shared__ __align__(16) u16 Ah [2*8192];
  __shared__ __align__(16) u16 BhS[2*4096];
  __shared__ __align__(16) u16 BlS[2*4096];

  int bx = blockIdx.x;
  // XCD-grouped swizzle: xcd owns a contiguous mt range; nt iterates fastest
  // so the 8 blocks sharing an enc panel run on the SAME XCD's L2.
  int xcd = bx & 7, lb = bx >> 3;
  int nt = lb & 7, mtl = lb >> 3;          // nt 0..7, mtl 0..31
  int mt = xcd * 32 + mtl;
  int m0 = mt * 256, n0 = nt * 128;

  int tid = threadIdx.x;
  int w = tid >> 6, lane = tid & 63;
  int wm = (w & 1) * 128, wn = (w >> 1) * 64;
  int q = lane >> 4, c = lane & 15;
  int fch = (q ^ ((c >> 1) & 3)) * 8;      // frag phys-chunk offset (u16 units)

  f32x4 zero = {0.f, 0.f, 0.f, 0.f};
  f32x4 acc[8][4];
#pragma unroll
  for (int i = 0; i < 8; ++i)
#pragma unroll
    for (int j = 0; j < 4; ++j) acc[i][j] = zero;

  // ---- A staging map (coalesced: 8 threads cover one 32-f32 row) ----
  int arow = tid >> 3, ac8 = tid & 7;
  const float4* Abase = (const float4*)enc + ((size_t)(m0 + arow) * Ee >> 2) + ac8;
  // ((arow+32p)>>1)&3 == (arow>>1)&3 since 16p % 4 == 0 -> swizzle pass-invariant
  int awbase = arow * 32 + (((ac8 >> 1) ^ ((arow >> 1) & 3)) << 3) + (ac8 & 1) * 4;

  // ---- B staging map (global_load_lds, pre-swizzled source) ----
  int cidx0 = w * 2, cidx1 = w * 2 + 1;
  int r0 = cidx0 * 16 + (lane >> 2);
  int r1 = cidx1 * 16 + (lane >> 2);
  int lg0 = ((lane & 3) ^ ((r0 >> 1) & 3)) * 8;
  int lg1 = ((lane & 3) ^ ((r1 >> 1) & 3)) * 8;
  const u16* Bh0 = Wt_hi + (size_t)(n0 + r0) * Ee + lg0;
  const u16* Bh1 = Wt_hi + (size_t)(n0 + r1) * Ee + lg1;
  const u16* Bl0 = Wt_lo + (size_t)(n0 + r0) * Ee + lg0;
  const u16* Bl1 = Wt_lo + (size_t)(n0 + r1) * Ee + lg1;
  int bws0 = cidx0 * 512, bws1 = cidx1 * 512;   // u16 LDS offsets (wave-uniform)

  float4 avA[8], avB[8];   // two in-flight A reg sets (2-step-deep prefetch)

  // ---- prologue: stage A(0)+B(0) into buffer 0; issue avB = A(1) loads ----
  {
    glds16(Bh0, &BhS[bws0]);
    glds16(Bh1, &BhS[bws1]);
    glds16(Bl0, &BlS[bws0]);
    glds16(Bl1, &BlS[bws1]);
    float4 avP[8];
#pragma unroll
    for (int p = 0; p < 8; ++p) avP[p] = Abase[(size_t)(32 * p) * (Ee / 4)];
#pragma unroll
    for (int p = 0; p < 8; ++p)
      avB[p] = Abase[(size_t)(32 * p) * (Ee / 4) + 8];          // A(1)
#pragma unroll
    for (int p = 0; p < 8; ++p)
      *(uint2*)&Ah[awbase + 1024 * p] =
          make_uint2(pack2h(avP[p].x, avP[p].y), pack2h(avP[p].z, avP[p].w));
    __syncthreads();   // buffer 0 ready (glds + A writes drained)
  }

  // GEMM_STEP(kt, PAR, AVL, AVP):
  //   top:  issue AVL = A(kt+2) loads; issue glds B(kt+1) -> buf^1
  //   mid:  ds_read frags(buf) ; 8x hi-MFMA then 8x lo-MFMA per j
  //   tail: pack AVP (= A(kt+1), loaded one step ago) -> A-LDS buf^1; barrier
#define GEMM_STEP(KT, PAR, AVL, AVP)                                           \
  {                                                                            \
    const int curA = (PAR) * 8192, nxtA = 8192 - curA;                         \
    const int curB = (PAR) * 4096, nxtB = 4096 - curB;                         \
    if ((KT) < 30) {                                                           \
      _Pragma("unroll")                                                        \
      for (int p = 0; p < 8; ++p)                                              \
        AVL[p] = Abase[(size_t)(32 * p) * (Ee / 4) + (size_t)((KT) + 2) * 8];  \
    }                                                                          \
    if ((KT) < 31) {                                                           \
      size_t ko = (size_t)((KT) + 1) * 32;                                     \
      glds16(Bh0 + ko, &BhS[nxtB + bws0]);                                     \
      glds16(Bh1 + ko, &BhS[nxtB + bws1]);                                     \
      glds16(Bl0 + ko, &BlS[nxtB + bws0]);                                     \
      glds16(Bl1 + ko, &BlS[nxtB + bws1]);                                     \
    }                                                                          \
    f16x8 aF[8];                                                               \
    _Pragma("unroll")                                                          \
    for (int i = 0; i < 8; ++i)                                                \
      aF[i] = *(const f16x8*)&Ah[curA + (wm + i * 16 + c) * 32 + fch];         \
    __builtin_amdgcn_s_setprio(1);                                             \
    _Pragma("unroll")                                                          \
    for (int j = 0; j < 4; ++j) {                                              \
      f16x8 bH = *(const f16x8*)&BhS[curB + (wn + j * 16 + c) * 32 + fch];     \
      f16x8 bL = *(const f16x8*)&BlS[curB + (wn + j * 16 + c) * 32 + fch];     \
      _Pragma("unroll")                                                        \
      for (int i = 0; i < 8; ++i)                                              \
        acc[i][j] = __builtin_amdgcn_mfma_f32_16x16x32_f16(aF[i], bH, acc[i][j], 0, 0, 0); \
      _Pragma("unroll")                                                        \
      for (int i = 0; i < 8; ++i)                                              \
        acc[i][j] = __builtin_amdgcn_mfma_f32_16x16x32_f16(aF[i], bL, acc[i][j], 0, 0, 0); \
    }                                                                          \
    __builtin_amdgcn_s_setprio(0);                                             \
    if ((KT) < 31) {                                                           \
      _Pragma("unroll")                                                        \
      for (int p = 0; p < 8; ++p)                                              \
        *(uint2*)&Ah[nxtA + awbase + 1024 * p] =                               \
            make_uint2(pack2h(AVP[p].x, AVP[p].y), pack2h(AVP[p].z, AVP[p].w));\
    }                                                                          \
    __syncthreads();                                                           \
  }

#pragma unroll 1
  for (int ks = 0; ks < 16; ++ks) {
    int kt0 = 2 * ks;
    GEMM_STEP(kt0, 0, avA, avB)        // consumes avB = A(kt0+1), loads avA = A(kt0+2)
    GEMM_STEP(kt0 + 1, 1, avB, avA)    // consumes avA = A(kt0+2), loads avB = A(kt0+3)
  }
#undef GEMM_STEP

  // epilogue: z -> tanh -> store bf16 ht; fused score partial (ctx dot)
  int bidx = m0 >> 11;                   // T = 2048; 256-row tile stays in one batch
  float ctxv[4], biasv[4];
#pragma unroll
  for (int j = 0; j < 4; ++j) {
    int col = n0 + wn + j * 16 + c;
    ctxv[j]  = ctx[bidx * Ee + col];
    biasv[j] = bias[col];
  }
#pragma unroll
  for (int i = 0; i < 8; ++i) {
#pragma unroll
    for (int r = 0; r < 4; ++r) {
      int rowG = m0 + wm + i * 16 + q * 4 + r;   // C/D: row=(lane>>4)*4+reg, col=lane&15
      u16* hrow = ht + (size_t)rowG * Ee + n0 + wn + c;
      float s = 0.f;
#pragma unroll
      for (int j = 0; j < 4; ++j) {
        float h = tanh_fast(acc[i][j][r] + biasv[j]);
        __hip_bfloat16 hb = __float2bfloat16(h);
        hrow[j * 16] = *(u16*)&hb;
        s += h * ctxv[j];
      }
      s += __shfl_xor(s, 1); s += __shfl_xor(s, 2);
      s += __shfl_xor(s, 4); s += __shfl_xor(s, 8);
      if (c == 0) atomicAdd(&scores[rowG], s);
    }
  }
}

// ---------------- K2: softmax over T per batch row ----------------
__global__ __launch_bounds__(256) void softmax_t(const float* __restrict__ scores,
                                                 float* __restrict__ at) {
  __shared__ float red[256];
  int b = blockIdx.x, tid = threadIdx.x;
  float v[8];
  float mx = -3.0e38f;
#pragma unroll
  for (int i = 0; i < 8; ++i) {
    v[i] = scores[b * Tt + i * 256 + tid];
    mx = fmaxf(mx, v[i]);
  }
  red[tid] = mx; __syncthreads();
  for (int s = 128; s > 0; s >>= 1) {
    if (tid < s) red[tid] = fmaxf(red[tid], red[tid + s]);
    __syncthreads();
  }
  mx = red[0]; __syncthreads();
  float sum = 0.f;
#pragma unroll
  for (int i = 0; i < 8; ++i) { v[i] = __expf(v[i] - mx); sum += v[i]; }
  red[tid] = sum; __syncthreads();
  for (int s = 128; s > 0; s >>= 1) {
    if (tid < s) red[tid] += red[tid + s];
    __syncthreads();
  }
  float inv = 1.0f / red[0];
#pragma unroll
  for (int i = 0; i < 8; ++i) at[b * Tt + i * 256 + tid] = v[i] * inv;
}

// ---------------- K3: partial[b,tc,e] = sum_{t in chunk} at[b,t] * ht[b,t,e] ----------------
__global__ __launch_bounds__(256) void weighted_sum(const u16* __restrict__ ht,
                                                    const float* __restrict__ at,
                                                    float* __restrict__ part) {
  __shared__ float ats[64];
  int bx = blockIdx.x;
  int b = bx >> 5, tc = bx & 31;
  int tid = threadIdx.x;
  if (tid < 64) ats[tid] = at[b * Tt + tc * 64 + tid];
  __syncthreads();
  int e0 = tid * 4;
  const u16* base = ht + (size_t)(b * Tt + tc * 64) * Ee + e0;
  float s0 = 0.f, s1 = 0.f, s2 = 0.f, s3 = 0.f;
#pragma unroll 4
  for (int t = 0; t < 64; ++t) {
    float a = ats[t];
    uint2 u = *(const uint2*)(base + (size_t)t * Ee);
    s0 += a * __uint_as_float(u.x << 16);
    s1 += a * __uint_as_float(u.x & 0xffff0000u);
    s2 += a * __uint_as_float(u.y << 16);
    s3 += a * __uint_as_float(u.y & 0xffff0000u);
  }
  float4 out4 = make_float4(s0, s1, s2, s3);
  *(float4*)(part + ((size_t)(b * 32 + tc) * Ee + e0)) = out4;
}

// ---------------- K4: out[b,e] = sum_tc part[b,tc,e] ----------------
__global__ __launch_bounds__(256) void reduce_part(const float* __restrict__ part,
                                                   float* __restrict__ out) {
  int b = blockIdx.x, tid = threadIdx.x;
  float4 s = make_float4(0.f, 0.f, 0.f, 0.f);
#pragma unroll
  for (int tc = 0; tc < 32; ++tc) {
    float4 p = ((const float4*)(part + (size_t)(b * 32 + tc) * Ee))[tid];
    s.x += p.x; s.y += p.y; s.z += p.z; s.w += p.w;
  }
  ((float4*)(out + (size_t)b * Ee))[tid] = s;
}

extern "C" void kernel_launch(void* const* d_in, const int* in_sizes, int n_in,
                              void* d_out, int out_size, void* d_ws, size_t ws_size,
                              hipStream_t stream) {
  const float* enc  = (const float*)d_in[0];
  const float* ctx  = (const float*)d_in[1];
  const float* W    = (const float*)d_in[2];
  const float* bias = (const float*)d_in[3];
  float* out = (float*)d_out;

  char* ws = (char*)d_ws;
  u16* Wt_hi = (u16*)(ws);
  u16* Wt_lo = (u16*)(ws + (size_t)2 * 1024 * 1024);
  u16* ht    = (u16*)(ws + (size_t)4 * 1024 * 1024);
  float* scores = (float*)(ws + (size_t)4 * 1024 * 1024 + (size_t)Mm * Ee * 2);
  float* at     = scores + Mm;
  // part reuses the Wt region (dead after the GEMM): 32*32*1024 fp32 = 4 MB
  float* part   = (float*)ws;

  hipMemsetAsync(scores, 0, (size_t)Mm * sizeof(float), stream);

  wt_convert<<<dim3(32, 32), dim3(32, 8), 0, stream>>>(W, Wt_hi, Wt_lo);
  gemm_tanh_score<<<dim3(2048), dim3(256), 0, stream>>>(enc, ctx, bias, Wt_hi, Wt_lo, ht, scores);
  softmax_t<<<dim3(32), dim3(256), 0, stream>>>(scores, at);
  weighted_sum<<<dim3(1024), dim3(256), 0, stream>>>(ht, at, part);
  reduce_part<<<dim3(32), dim3(256), 0, stream>>>(part, out);
}

// Round 5
// 691.113 us; speedup vs baseline: 2.2172x; 2.2172x over previous
//
#include <hip/hip_runtime.h>
#include <hip/hip_bf16.h>
#include <math.h>

typedef unsigned short u16;
typedef unsigned int   u32;
typedef _Float16 f16x8 __attribute__((ext_vector_type(8)));
typedef float f32x4  __attribute__((ext_vector_type(4)));

#define Bb 32
#define Tt 2048
#define Ee 1024
#define Mm (Bb*Tt)

__device__ __forceinline__ float tanh_fast(float x) {
  float ax = fminf(fabsf(x), 15.0f);
  float e  = __expf(2.0f * ax);
  float t  = 1.0f - 2.0f / (e + 1.0f);
  return copysignf(t, x);
}

__device__ __forceinline__ u32 pack2h(float a, float b) {
  _Float16 ha = (_Float16)a, hb = (_Float16)b;   // v_cvt_f16_f32 (RTN) — numerics preserved
  return (u32)__builtin_bit_cast(u16, ha) | ((u32)__builtin_bit_cast(u16, hb) << 16);
}

// async global->LDS, 16B per lane; LDS dest is wave-uniform base + lane*16
__device__ __forceinline__ void glds16(const u16* g, u16* l) {
  __builtin_amdgcn_global_load_lds(
      (const __attribute__((address_space(1))) void*)g,
      (__attribute__((address_space(3))) void*)l, 16, 0, 0);
}

// ---------------- K0a: enc (fp32) -> enc16 (fp16, RTN — same cast as pack2h) ----------------
__global__ __launch_bounds__(256) void enc_convert(const float* __restrict__ enc,
                                                   u16* __restrict__ enc16) {
  size_t i = ((size_t)blockIdx.x * 256 + threadIdx.x) * 8;
  size_t stride = (size_t)gridDim.x * 256 * 8;
  size_t total = (size_t)Mm * Ee;
  for (; i < total; i += stride) {
    float4 f0 = *(const float4*)(enc + i);
    float4 f1 = *(const float4*)(enc + i + 4);
    uint4 o = make_uint4(pack2h(f0.x, f0.y), pack2h(f0.z, f0.w),
                         pack2h(f1.x, f1.y), pack2h(f1.z, f1.w));
    *(uint4*)(enc16 + i) = o;
  }
}

// ---------------- K0b: W (K x N fp32) -> Wt_hi/Wt_lo (N x K fp16 split) ----------------
__global__ __launch_bounds__(256) void wt_convert(const float* __restrict__ W,
                                                  u16* __restrict__ Wt_hi,
                                                  u16* __restrict__ Wt_lo) {
  __shared__ float tile[32][33];
  int n0 = blockIdx.x * 32, k0 = blockIdx.y * 32;
  int tx = threadIdx.x, ty = threadIdx.y;   // 32 x 8
#pragma unroll
  for (int i = 0; i < 4; ++i)
    tile[ty + 8*i][tx] = W[(size_t)(k0 + ty + 8*i) * Ee + n0 + tx];
  __syncthreads();
#pragma unroll
  for (int i = 0; i < 4; ++i) {
    float v = tile[tx][ty + 8*i];
    _Float16 hi = (_Float16)v;
    float rem = v - (float)hi;
    _Float16 lo = (_Float16)rem;
    size_t idx = (size_t)(n0 + ty + 8*i) * Ee + k0 + tx;
    Wt_hi[idx] = __builtin_bit_cast(u16, hi);
    Wt_lo[idx] = __builtin_bit_cast(u16, lo);
  }
}

// ---------------- K1 (fast path): ht = tanh(enc@W + b), fused score ----------------
// 256x128 tile, BK=32, 4 waves x wave-tile 128x64. Round-5 design:
// ALL staging via global_load_lds from pre-converted enc16 (round-4's reg-path
// deepening spilled to scratch: WRITE_SIZE 147MB->1.76GB). No reg staging, no
// pack VALU in the loop.
//   - A triple-buffered (48KB), glds issued TWO steps ahead -> enc HBM latency
//     (~900cyc) fully covered with zero register cost.
//   - B double-buffered (32KB), glds one step ahead (Wt is 4MB, L2-resident).
//   - tail: counted s_waitcnt vmcnt(4) + raw s_barrier — A(kt+2) stays in
//     flight ACROSS the barrier (T4). vmcnt ledger: steady outstanding at tail
//     = B(kt+1)x4 + A(kt+2)x4 + A(kt+1)x4(from kt-1) = 12; vmcnt(4) retires
//     the 8 oldest = A(kt+1),B(kt+1); kt=30 drains vmcnt(0).
//   - de-paired hi/lo MFMAs (8x hi then 8x lo per j): same-acc dependency gap
//     grows from 0 to 8 independent MFMAs; per-acc add order unchanged ->
//     bit-identical numerics.
// LDS 80KB -> 2 blocks/CU. 16B-chunk XOR swizzle (phys = logical ^ ((row>>1)&3)),
// applied via pre-swizzled GLOBAL source (glds dest must be linear): measured
// 0 bank conflicts in rounds 1-3.
__global__ __launch_bounds__(256, 2) void gemm_tanh_score16(
    const u16* __restrict__ enc16, const float* __restrict__ ctx,
    const float* __restrict__ bias,
    const u16* __restrict__ Wt_hi, const u16* __restrict__ Wt_lo,
    u16* __restrict__ ht, float* __restrict__ scores) {
  __shared__ __align__(16) u16 Ah [3*8192];   // 48 KB, triple buffer
  __shared__ __align__(16) u16 BhS[2*4096];   // 16 KB, double buffer
  __shared__ __align__(16) u16 BlS[2*4096];   // 16 KB, double buffer

  int bx = blockIdx.x;
  // XCD-grouped swizzle: xcd owns a contiguous mt range; nt iterates fastest
  // so the 8 blocks sharing an enc panel run on the SAME XCD's L2.
  int xcd = bx & 7, lb = bx >> 3;
  int nt = lb & 7, mtl = lb >> 3;          // nt 0..7, mtl 0..31
  int mt = xcd * 32 + mtl;
  int m0 = mt * 256, n0 = nt * 128;

  int tid = threadIdx.x;
  int w = tid >> 6, lane = tid & 63;
  int wm = (w & 1) * 128, wn = (w >> 1) * 64;
  int q = lane >> 4, c = lane & 15;
  int fch = (q ^ ((c >> 1) & 3)) * 8;      // frag phys-chunk offset (u16 units)

  f32x4 zero = {0.f, 0.f, 0.f, 0.f};
  f32x4 acc[8][4];
#pragma unroll
  for (int i = 0; i < 8; ++i)
#pragma unroll
    for (int j = 0; j < 4; ++j) acc[i][j] = zero;

  // ---- A staging map (glds, pre-swizzled source) ----
  // 16KB tile = 16 chunks of 1KB; wave w covers cidx = 4w..4w+3.
  // lane l in chunk cidx: row = cidx*16 + (l>>2), 16B slot (l&3).
  // swz(row) = (row>>1)&3 = (l>>3)&3  (cidx*16>>1 is a multiple of 4).
  int lgA = (((lane & 3) ^ ((lane >> 3) & 3))) * 8;
  int arw = (lane >> 2);                    // row within 16-row chunk group
  const u16* A0 = enc16 + (size_t)(m0 + w * 64 +  0 + arw) * Ee + lgA;
  const u16* A1 = enc16 + (size_t)(m0 + w * 64 + 16 + arw) * Ee + lgA;
  const u16* A2 = enc16 + (size_t)(m0 + w * 64 + 32 + arw) * Ee + lgA;
  const u16* A3 = enc16 + (size_t)(m0 + w * 64 + 48 + arw) * Ee + lgA;
  int aws0 = (w * 4 + 0) * 512, aws1 = (w * 4 + 1) * 512;   // u16 LDS offsets
  int aws2 = (w * 4 + 2) * 512, aws3 = (w * 4 + 3) * 512;

  // ---- B staging map (glds, pre-swizzled source) ----
  int cidx0 = w * 2, cidx1 = w * 2 + 1;
  int r0 = cidx0 * 16 + (lane >> 2);
  int r1 = cidx1 * 16 + (lane >> 2);
  int lg0 = ((lane & 3) ^ ((r0 >> 1) & 3)) * 8;
  int lg1 = ((lane & 3) ^ ((r1 >> 1) & 3)) * 8;
  const u16* Bh0 = Wt_hi + (size_t)(n0 + r0) * Ee + lg0;
  const u16* Bh1 = Wt_hi + (size_t)(n0 + r1) * Ee + lg1;
  const u16* Bl0 = Wt_lo + (size_t)(n0 + r0) * Ee + lg0;
  const u16* Bl1 = Wt_lo + (size_t)(n0 + r1) * Ee + lg1;
  int bws0 = cidx0 * 512, bws1 = cidx1 * 512;

  // ---- prologue: glds A(0), B(0), A(1); counted wait; barrier ----
  {
    glds16(A0, &Ah[0 + aws0]); glds16(A1, &Ah[0 + aws1]);
    glds16(A2, &Ah[0 + aws2]); glds16(A3, &Ah[0 + aws3]);
    glds16(Bh0, &BhS[bws0]);   glds16(Bh1, &BhS[bws1]);
    glds16(Bl0, &BlS[bws0]);   glds16(Bl1, &BlS[bws1]);
    glds16(A0 + 32, &Ah[8192 + aws0]); glds16(A1 + 32, &Ah[8192 + aws1]);
    glds16(A2 + 32, &Ah[8192 + aws2]); glds16(A3 + 32, &Ah[8192 + aws3]);
    asm volatile("s_waitcnt vmcnt(4)" ::: "memory");   // A(0),B(0) landed; A(1) in flight
    __builtin_amdgcn_s_barrier();
    __builtin_amdgcn_sched_barrier(0);
  }

  int a0 = 0, a1 = 8192, a2 = 16384;   // A buffer rotation (u16 offsets)

#pragma unroll 1
  for (int kt = 0; kt < 32; ++kt) {
    int curB = (kt & 1) * 4096, nxtB = 4096 - curB;
    if (kt < 31) {                      // B(kt+1) -> buf^1
      size_t ko = (size_t)(kt + 1) * 32;
      glds16(Bh0 + ko, &BhS[nxtB + bws0]);
      glds16(Bh1 + ko, &BhS[nxtB + bws1]);
      glds16(Bl0 + ko, &BlS[nxtB + bws0]);
      glds16(Bl1 + ko, &BlS[nxtB + bws1]);
    }
    if (kt < 30) {                      // A(kt+2) -> a2 (2-deep prefetch)
      size_t ka = (size_t)(kt + 2) * 32;
      glds16(A0 + ka, &Ah[a2 + aws0]);
      glds16(A1 + ka, &Ah[a2 + aws1]);
      glds16(A2 + ka, &Ah[a2 + aws2]);
      glds16(A3 + ka, &Ah[a2 + aws3]);
    }

    f16x8 aF[8];
#pragma unroll
    for (int i = 0; i < 8; ++i)
      aF[i] = *(const f16x8*)&Ah[a0 + (wm + i * 16 + c) * 32 + fch];

    __builtin_amdgcn_s_setprio(1);
#pragma unroll
    for (int j = 0; j < 4; ++j) {
      f16x8 bH = *(const f16x8*)&BhS[curB + (wn + j * 16 + c) * 32 + fch];
      f16x8 bL = *(const f16x8*)&BlS[curB + (wn + j * 16 + c) * 32 + fch];
#pragma unroll
      for (int i = 0; i < 8; ++i)
        acc[i][j] = __builtin_amdgcn_mfma_f32_16x16x32_f16(aF[i], bH, acc[i][j], 0, 0, 0);
#pragma unroll
      for (int i = 0; i < 8; ++i)
        acc[i][j] = __builtin_amdgcn_mfma_f32_16x16x32_f16(aF[i], bL, acc[i][j], 0, 0, 0);
    }
    __builtin_amdgcn_s_setprio(0);

    // counted wait: A(kt+1)+B(kt+1) landed, A(kt+2) stays in flight across barrier
    if (kt < 30) asm volatile("s_waitcnt vmcnt(4)" ::: "memory");
    else         asm volatile("s_waitcnt vmcnt(0)" ::: "memory");
    __builtin_amdgcn_s_barrier();
    __builtin_amdgcn_sched_barrier(0);
    int tmp = a0; a0 = a1; a1 = a2; a2 = tmp;
  }

  // epilogue: z -> tanh -> store bf16 ht; fused score partial (ctx dot)
  int bidx = m0 >> 11;                   // T = 2048; 256-row tile stays in one batch
  float ctxv[4], biasv[4];
#pragma unroll
  for (int j = 0; j < 4; ++j) {
    int col = n0 + wn + j * 16 + c;
    ctxv[j]  = ctx[bidx * Ee + col];
    biasv[j] = bias[col];
  }
#pragma unroll
  for (int i = 0; i < 8; ++i) {
#pragma unroll
    for (int r = 0; r < 4; ++r) {
      int rowG = m0 + wm + i * 16 + q * 4 + r;   // C/D: row=(lane>>4)*4+reg, col=lane&15
      u16* hrow = ht + (size_t)rowG * Ee + n0 + wn + c;
      float s = 0.f;
#pragma unroll
      for (int j = 0; j < 4; ++j) {
        float h = tanh_fast(acc[i][j][r] + biasv[j]);
        __hip_bfloat16 hb = __float2bfloat16(h);
        hrow[j * 16] = *(u16*)&hb;
        s += h * ctxv[j];
      }
      s += __shfl_xor(s, 1); s += __shfl_xor(s, 2);
      s += __shfl_xor(s, 4); s += __shfl_xor(s, 8);
      if (c == 0) atomicAdd(&scores[rowG], s);
    }
  }
}

// ---------------- K1 (fallback, verbatim round-2 378µs kernel): used if ws too small ----------------
__global__ __launch_bounds__(256, 2) void gemm_tanh_score_f32(
    const float* __restrict__ enc, const float* __restrict__ ctx,
    const float* __restrict__ bias,
    const u16* __restrict__ Wt_hi, const u16* __restrict__ Wt_lo,
    u16* __restrict__ ht, float* __restrict__ scores) {
  __shared__ __align__(16) u16 Ah [2*8192];
  __shared__ __align__(16) u16 BhS[2*4096];
  __shared__ __align__(16) u16 BlS[2*4096];

  int bx = blockIdx.x;
  int xcd = bx & 7, lb = bx >> 3;
  int nt = lb & 7, mtl = lb >> 3;
  int mt = xcd * 32 + mtl;
  int m0 = mt * 256, n0 = nt * 128;

  int tid = threadIdx.x;
  int w = tid >> 6, lane = tid & 63;
  int wm = (w & 1) * 128, wn = (w >> 1) * 64;
  int q = lane >> 4, c = lane & 15;
  int fch = (q ^ ((c >> 1) & 3)) * 8;

  f32x4 zero = {0.f, 0.f, 0.f, 0.f};
  f32x4 acc[8][4];
#pragma unroll
  for (int i = 0; i < 8; ++i)
#pragma unroll
    for (int j = 0; j < 4; ++j) acc[i][j] = zero;

  int arow = tid >> 3, ac8 = tid & 7;
  const float4* Abase = (const float4*)enc + ((size_t)(m0 + arow) * Ee >> 2) + ac8;
  int awbase = arow * 32 + (((ac8 >> 1) ^ ((arow >> 1) & 3)) << 3) + (ac8 & 1) * 4;

  int cidx0 = w * 2, cidx1 = w * 2 + 1;
  int r0 = cidx0 * 16 + (lane >> 2);
  int r1 = cidx1 * 16 + (lane >> 2);
  int lg0 = ((lane & 3) ^ ((r0 >> 1) & 3)) * 8;
  int lg1 = ((lane & 3) ^ ((r1 >> 1) & 3)) * 8;
  const u16* Bh0 = Wt_hi + (size_t)(n0 + r0) * Ee + lg0;
  const u16* Bh1 = Wt_hi + (size_t)(n0 + r1) * Ee + lg1;
  const u16* Bl0 = Wt_lo + (size_t)(n0 + r0) * Ee + lg0;
  const u16* Bl1 = Wt_lo + (size_t)(n0 + r1) * Ee + lg1;
  int bws0 = cidx0 * 512, bws1 = cidx1 * 512;

  {
    glds16(Bh0, &BhS[bws0]);
    glds16(Bh1, &BhS[bws1]);
    glds16(Bl0, &BlS[bws0]);
    glds16(Bl1, &BlS[bws1]);
    float4 f0 = Abase[0], f1 = Abase[(size_t)32 * (Ee/4)],
           f2 = Abase[(size_t)64 * (Ee/4)], f3 = Abase[(size_t)96 * (Ee/4)];
    float4 f4 = Abase[(size_t)128 * (Ee/4)], f5 = Abase[(size_t)160 * (Ee/4)],
           f6 = Abase[(size_t)192 * (Ee/4)], f7 = Abase[(size_t)224 * (Ee/4)];
    *(uint2*)&Ah[awbase + 0]    = make_uint2(pack2h(f0.x,f0.y), pack2h(f0.z,f0.w));
    *(uint2*)&Ah[awbase + 1024] = make_uint2(pack2h(f1.x,f1.y), pack2h(f1.z,f1.w));
    *(uint2*)&Ah[awbase + 2048] = make_uint2(pack2h(f2.x,f2.y), pack2h(f2.z,f2.w));
    *(uint2*)&Ah[awbase + 3072] = make_uint2(pack2h(f3.x,f3.y), pack2h(f3.z,f3.w));
    *(uint2*)&Ah[awbase + 4096] = make_uint2(pack2h(f4.x,f4.y), pack2h(f4.z,f4.w));
    *(uint2*)&Ah[awbase + 5120] = make_uint2(pack2h(f5.x,f5.y), pack2h(f5.z,f5.w));
    *(uint2*)&Ah[awbase + 6144] = make_uint2(pack2h(f6.x,f6.y), pack2h(f6.z,f6.w));
    *(uint2*)&Ah[awbase + 7168] = make_uint2(pack2h(f7.x,f7.y), pack2h(f7.z,f7.w));
    __syncthreads();
  }

#pragma unroll 2
  for (int kt = 0; kt < 32; ++kt) {
    int curA = (kt & 1) * 8192, nxtA = 8192 - curA;
    int curB = (kt & 1) * 4096, nxtB = 4096 - curB;
    float4 av[8];
    if (kt < 31) {
#pragma unroll
      for (int p = 0; p < 8; ++p)
        av[p] = Abase[(size_t)(32 * p) * (Ee / 4) + (size_t)(kt + 1) * 8];
      size_t ko = (size_t)(kt + 1) * 32;
      glds16(Bh0 + ko, &BhS[nxtB + bws0]);
      glds16(Bh1 + ko, &BhS[nxtB + bws1]);
      glds16(Bl0 + ko, &BlS[nxtB + bws0]);
      glds16(Bl1 + ko, &BlS[nxtB + bws1]);
    }

    f16x8 aF[8];
#pragma unroll
    for (int i = 0; i < 8; ++i)
      aF[i] = *(const f16x8*)&Ah[curA + (wm + i * 16 + c) * 32 + fch];

    __builtin_amdgcn_s_setprio(1);
#pragma unroll
    for (int j = 0; j < 4; ++j) {
      f16x8 bH = *(const f16x8*)&BhS[curB + (wn + j * 16 + c) * 32 + fch];
      f16x8 bL = *(const f16x8*)&BlS[curB + (wn + j * 16 + c) * 32 + fch];
#pragma unroll
      for (int i = 0; i < 8; ++i) {
        acc[i][j] = __builtin_amdgcn_mfma_f32_16x16x32_f16(aF[i], bH, acc[i][j], 0, 0, 0);
        acc[i][j] = __builtin_amdgcn_mfma_f32_16x16x32_f16(aF[i], bL, acc[i][j], 0, 0, 0);
      }
    }
    __builtin_amdgcn_s_setprio(0);

    if (kt < 31) {
#pragma unroll
      for (int p = 0; p < 8; ++p)
        *(uint2*)&Ah[nxtA + awbase + 1024 * p] =
            make_uint2(pack2h(av[p].x, av[p].y), pack2h(av[p].z, av[p].w));
    }
    __syncthreads();
  }

  int bidx = m0 >> 11;
  float ctxv[4], biasv[4];
#pragma unroll
  for (int j = 0; j < 4; ++j) {
    int col = n0 + wn + j * 16 + c;
    ctxv[j]  = ctx[bidx * Ee + col];
    biasv[j] = bias[col];
  }
#pragma unroll
  for (int i = 0; i < 8; ++i) {
#pragma unroll
    for (int r = 0; r < 4; ++r) {
      int rowG = m0 + wm + i * 16 + q * 4 + r;
      u16* hrow = ht + (size_t)rowG * Ee + n0 + wn + c;
      float s = 0.f;
#pragma unroll
      for (int j = 0; j < 4; ++j) {
        float h = tanh_fast(acc[i][j][r] + biasv[j]);
        __hip_bfloat16 hb = __float2bfloat16(h);
        hrow[j * 16] = *(u16*)&hb;
        s += h * ctxv[j];
      }
      s += __shfl_xor(s, 1); s += __shfl_xor(s, 2);
      s += __shfl_xor(s, 4); s += __shfl_xor(s, 8);
      if (c == 0) atomicAdd(&scores[rowG], s);
    }
  }
}

// ---------------- K2: softmax over T per batch row ----------------
__global__ __launch_bounds__(256) void softmax_t(const float* __restrict__ scores,
                                                 float* __restrict__ at) {
  __shared__ float red[256];
  int b = blockIdx.x, tid = threadIdx.x;
  float v[8];
  float mx = -3.0e38f;
#pragma unroll
  for (int i = 0; i < 8; ++i) {
    v[i] = scores[b * Tt + i * 256 + tid];
    mx = fmaxf(mx, v[i]);
  }
  red[tid] = mx; __syncthreads();
  for (int s = 128; s > 0; s >>= 1) {
    if (tid < s) red[tid] = fmaxf(red[tid], red[tid + s]);
    __syncthreads();
  }
  mx = red[0]; __syncthreads();
  float sum = 0.f;
#pragma unroll
  for (int i = 0; i < 8; ++i) { v[i] = __expf(v[i] - mx); sum += v[i]; }
  red[tid] = sum; __syncthreads();
  for (int s = 128; s > 0; s >>= 1) {
    if (tid < s) red[tid] += red[tid + s];
    __syncthreads();
  }
  float inv = 1.0f / red[0];
#pragma unroll
  for (int i = 0; i < 8; ++i) at[b * Tt + i * 256 + tid] = v[i] * inv;
}

// ---------------- K3: partial[b,tc,e] = sum_{t in chunk} at[b,t] * ht[b,t,e] ----------------
__global__ __launch_bounds__(256) void weighted_sum(const u16* __restrict__ ht,
                                                    const float* __restrict__ at,
                                                    float* __restrict__ part) {
  __shared__ float ats[64];
  int bx = blockIdx.x;
  int b = bx >> 5, tc = bx & 31;
  int tid = threadIdx.x;
  if (tid < 64) ats[tid] = at[b * Tt + tc * 64 + tid];
  __syncthreads();
  int e0 = tid * 4;
  const u16* base = ht + (size_t)(b * Tt + tc * 64) * Ee + e0;
  float s0 = 0.f, s1 = 0.f, s2 = 0.f, s3 = 0.f;
#pragma unroll 4
  for (int t = 0; t < 64; ++t) {
    float a = ats[t];
    uint2 u = *(const uint2*)(base + (size_t)t * Ee);
    s0 += a * __uint_as_float(u.x << 16);
    s1 += a * __uint_as_float(u.x & 0xffff0000u);
    s2 += a * __uint_as_float(u.y << 16);
    s3 += a * __uint_as_float(u.y & 0xffff0000u);
  }
  float4 out4 = make_float4(s0, s1, s2, s3);
  *(float4*)(part + ((size_t)(b * 32 + tc) * Ee + e0)) = out4;
}

// ---------------- K4: out[b,e] = sum_tc part[b,tc,e] ----------------
__global__ __launch_bounds__(256) void reduce_part(const float* __restrict__ part,
                                                   float* __restrict__ out) {
  int b = blockIdx.x, tid = threadIdx.x;
  float4 s = make_float4(0.f, 0.f, 0.f, 0.f);
#pragma unroll
  for (int tc = 0; tc < 32; ++tc) {
    float4 p = ((const float4*)(part + (size_t)(b * 32 + tc) * Ee))[tid];
    s.x += p.x; s.y += p.y; s.z += p.z; s.w += p.w;
  }
  ((float4*)(out + (size_t)b * Ee))[tid] = s;
}

extern "C" void kernel_launch(void* const* d_in, const int* in_sizes, int n_in,
                              void* d_out, int out_size, void* d_ws, size_t ws_size,
                              hipStream_t stream) {
  const float* enc  = (const float*)d_in[0];
  const float* ctx  = (const float*)d_in[1];
  const float* W    = (const float*)d_in[2];
  const float* bias = (const float*)d_in[3];
  float* out = (float*)d_out;

  char* ws = (char*)d_ws;
  u16* Wt_hi = (u16*)(ws);
  u16* Wt_lo = (u16*)(ws + (size_t)2 * 1024 * 1024);
  u16* ht    = (u16*)(ws + (size_t)4 * 1024 * 1024);
  float* scores = (float*)(ws + (size_t)4 * 1024 * 1024 + (size_t)Mm * Ee * 2);
  float* at     = scores + Mm;
  u16* enc16 = (u16*)(ws + (size_t)4 * 1024 * 1024 + (size_t)Mm * Ee * 2
                         + (size_t)Mm * 8);
  // part reuses the Wt region (dead after the GEMM): 32*32*1024 fp32 = 4 MB
  float* part = (float*)ws;

  size_t need = (size_t)4 * 1024 * 1024 + (size_t)Mm * Ee * 2 + (size_t)Mm * 8
              + (size_t)Mm * Ee * 2;   // Wt + ht + scores/at + enc16 ≈ 261 MB

  hipMemsetAsync(scores, 0, (size_t)Mm * sizeof(float), stream);
  wt_convert<<<dim3(32, 32), dim3(32, 8), 0, stream>>>(W, Wt_hi, Wt_lo);

  if (ws_size >= need) {
    enc_convert<<<dim3(8192), dim3(256), 0, stream>>>(enc, enc16);
    gemm_tanh_score16<<<dim3(2048), dim3(256), 0, stream>>>(enc16, ctx, bias,
                                                            Wt_hi, Wt_lo, ht, scores);
  } else {
    gemm_tanh_score_f32<<<dim3(2048), dim3(256), 0, stream>>>(enc, ctx, bias,
                                                              Wt_hi, Wt_lo, ht, scores);
  }
  softmax_t<<<dim3(32), dim3(256), 0, stream>>>(scores, at);
  weighted_sum<<<dim3(1024), dim3(256), 0, stream>>>(ht, at, part);
  reduce_part<<<dim3(32), dim3(256), 0, stream>>>(part, out);
}

// Round 6
// 690.537 us; speedup vs baseline: 2.2191x; 1.0008x over previous
//
#include <hip/hip_runtime.h>
#include <hip/hip_bf16.h>
#include <math.h>

typedef unsigned short u16;
typedef unsigned int   u32;
typedef _Float16 f16x8 __attribute__((ext_vector_type(8)));
typedef float f32x4  __attribute__((ext_vector_type(4)));

#define Bb 32
#define Tt 2048
#define Ee 1024
#define Mm (Bb*Tt)

__device__ __forceinline__ float tanh_fast(float x) {
  float ax = fminf(fabsf(x), 15.0f);
  float e  = __expf(2.0f * ax);
  float t  = 1.0f - 2.0f / (e + 1.0f);
  return copysignf(t, x);
}

__device__ __forceinline__ u32 pack2h(float a, float b) {
  _Float16 ha = (_Float16)a, hb = (_Float16)b;   // v_cvt_f16_f32 (RTN) — numerics preserved
  return (u32)__builtin_bit_cast(u16, ha) | ((u32)__builtin_bit_cast(u16, hb) << 16);
}

// async global->LDS, 16B per lane; LDS dest is wave-uniform base + lane*16
__device__ __forceinline__ void glds16(const u16* g, u16* l) {
  __builtin_amdgcn_global_load_lds(
      (const __attribute__((address_space(1))) void*)g,
      (__attribute__((address_space(3))) void*)l, 16, 0, 0);
}

// ---------------- K0a: enc (fp32) -> enc16 (fp16, RTN — same cast as pack2h) ----------------
__global__ __launch_bounds__(256) void enc_convert(const float* __restrict__ enc,
                                                   u16* __restrict__ enc16) {
  size_t i = ((size_t)blockIdx.x * 256 + threadIdx.x) * 8;
  size_t stride = (size_t)gridDim.x * 256 * 8;
  size_t total = (size_t)Mm * Ee;
  for (; i < total; i += stride) {
    float4 f0 = *(const float4*)(enc + i);
    float4 f1 = *(const float4*)(enc + i + 4);
    uint4 o = make_uint4(pack2h(f0.x, f0.y), pack2h(f0.z, f0.w),
                         pack2h(f1.x, f1.y), pack2h(f1.z, f1.w));
    *(uint4*)(enc16 + i) = o;
  }
}

// ---------------- K0b: W (K x N fp32) -> Wt_hi/Wt_lo (N x K fp16 split) ----------------
__global__ __launch_bounds__(256) void wt_convert(const float* __restrict__ W,
                                                  u16* __restrict__ Wt_hi,
                                                  u16* __restrict__ Wt_lo) {
  __shared__ float tile[32][33];
  int n0 = blockIdx.x * 32, k0 = blockIdx.y * 32;
  int tx = threadIdx.x, ty = threadIdx.y;   // 32 x 8
#pragma unroll
  for (int i = 0; i < 4; ++i)
    tile[ty + 8*i][tx] = W[(size_t)(k0 + ty + 8*i) * Ee + n0 + tx];
  __syncthreads();
#pragma unroll
  for (int i = 0; i < 4; ++i) {
    float v = tile[tx][ty + 8*i];
    _Float16 hi = (_Float16)v;
    float rem = v - (float)hi;
    _Float16 lo = (_Float16)rem;
    size_t idx = (size_t)(n0 + ty + 8*i) * Ee + k0 + tx;
    Wt_hi[idx] = __builtin_bit_cast(u16, hi);
    Wt_lo[idx] = __builtin_bit_cast(u16, lo);
  }
}

// ---------------- K1 (fast path): ht = tanh(enc@W + b), fused score ----------------
// 256x128 tile, BK=32, 4 waves x wave-tile 128x64, all staging via
// global_load_lds from pre-converted enc16. Round-6 change: within-wave
// read/MFMA software pipeline. Round-5 counters showed MFMA (2484 cyc) and
// LDS (~2300 cyc) per CU-step-pair running back-to-back (sum ≈ measured 5757,
// MfmaUtil 43%): each wave read all 16 frags, waited, then MFMA'd — and the
// per-step barrier phase-locks waves, so the CU alternated all-LDS/all-MFMA.
// Now cluster j+1's B-frags are read BETWEEN MFMA clusters (named ping-pong
// regs); compiler's fine-grained lgkmcnt lets cluster j compute while j+1's
// reads fly. Sync structure, buffers, numerics: unchanged from round 5
// (bit-identical results).
//   - A triple-buffered (48KB), glds TWO steps ahead; B double-buffered (32KB),
//     glds one step ahead (Wt 4MB, L2-resident).
//   - tail: counted s_waitcnt vmcnt(4) + raw s_barrier — A(kt+2) stays in
//     flight ACROSS the barrier (T4). Ledger: outstanding at tail = A(kt+1)x4
//     + B(kt+1)x4 + A(kt+2)x4 = 12; vmcnt(4) retires the 8 oldest.
//   - de-paired hi/lo MFMAs: same-acc dep gap = 8 independent MFMAs.
// LDS 80KB -> 2 blocks/CU. 16B-chunk XOR swizzle via pre-swizzled global
// source (glds dest linear): measured 0 bank conflicts.
__global__ __launch_bounds__(256, 2) void gemm_tanh_score16(
    const u16* __restrict__ enc16, const float* __restrict__ ctx,
    const float* __restrict__ bias,
    const u16* __restrict__ Wt_hi, const u16* __restrict__ Wt_lo,
    u16* __restrict__ ht, float* __restrict__ scores) {
  __shared__ __align__(16) u16 Ah [3*8192];   // 48 KB, triple buffer
  __shared__ __align__(16) u16 BhS[2*4096];   // 16 KB, double buffer
  __shared__ __align__(16) u16 BlS[2*4096];   // 16 KB, double buffer

  int bx = blockIdx.x;
  // XCD-grouped swizzle: xcd owns a contiguous mt range; nt iterates fastest
  // so the 8 blocks sharing an enc panel run on the SAME XCD's L2.
  int xcd = bx & 7, lb = bx >> 3;
  int nt = lb & 7, mtl = lb >> 3;          // nt 0..7, mtl 0..31
  int mt = xcd * 32 + mtl;
  int m0 = mt * 256, n0 = nt * 128;

  int tid = threadIdx.x;
  int w = tid >> 6, lane = tid & 63;
  int wm = (w & 1) * 128, wn = (w >> 1) * 64;
  int q = lane >> 4, c = lane & 15;
  int fch = (q ^ ((c >> 1) & 3)) * 8;      // frag phys-chunk offset (u16 units)

  f32x4 zero = {0.f, 0.f, 0.f, 0.f};
  f32x4 acc[8][4];
#pragma unroll
  for (int i = 0; i < 8; ++i)
#pragma unroll
    for (int j = 0; j < 4; ++j) acc[i][j] = zero;

  // ---- A staging map (glds, pre-swizzled source) ----
  int lgA = (((lane & 3) ^ ((lane >> 3) & 3))) * 8;
  int arw = (lane >> 2);
  const u16* A0 = enc16 + (size_t)(m0 + w * 64 +  0 + arw) * Ee + lgA;
  const u16* A1 = enc16 + (size_t)(m0 + w * 64 + 16 + arw) * Ee + lgA;
  const u16* A2 = enc16 + (size_t)(m0 + w * 64 + 32 + arw) * Ee + lgA;
  const u16* A3 = enc16 + (size_t)(m0 + w * 64 + 48 + arw) * Ee + lgA;
  int aws0 = (w * 4 + 0) * 512, aws1 = (w * 4 + 1) * 512;
  int aws2 = (w * 4 + 2) * 512, aws3 = (w * 4 + 3) * 512;

  // ---- B staging map (glds, pre-swizzled source) ----
  int cidx0 = w * 2, cidx1 = w * 2 + 1;
  int r0 = cidx0 * 16 + (lane >> 2);
  int r1 = cidx1 * 16 + (lane >> 2);
  int lg0 = ((lane & 3) ^ ((r0 >> 1) & 3)) * 8;
  int lg1 = ((lane & 3) ^ ((r1 >> 1) & 3)) * 8;
  const u16* Bh0 = Wt_hi + (size_t)(n0 + r0) * Ee + lg0;
  const u16* Bh1 = Wt_hi + (size_t)(n0 + r1) * Ee + lg1;
  const u16* Bl0 = Wt_lo + (size_t)(n0 + r0) * Ee + lg0;
  const u16* Bl1 = Wt_lo + (size_t)(n0 + r1) * Ee + lg1;
  int bws0 = cidx0 * 512, bws1 = cidx1 * 512;

  // ---- prologue: glds A(0), B(0), A(1); counted wait; barrier ----
  {
    glds16(A0, &Ah[0 + aws0]); glds16(A1, &Ah[0 + aws1]);
    glds16(A2, &Ah[0 + aws2]); glds16(A3, &Ah[0 + aws3]);
    glds16(Bh0, &BhS[bws0]);   glds16(Bh1, &BhS[bws1]);
    glds16(Bl0, &BlS[bws0]);   glds16(Bl1, &BlS[bws1]);
    glds16(A0 + 32, &Ah[8192 + aws0]); glds16(A1 + 32, &Ah[8192 + aws1]);
    glds16(A2 + 32, &Ah[8192 + aws2]); glds16(A3 + 32, &Ah[8192 + aws3]);
    asm volatile("s_waitcnt vmcnt(4)" ::: "memory");   // A(0),B(0) landed; A(1) in flight
    __builtin_amdgcn_s_barrier();
    __builtin_amdgcn_sched_barrier(0);
  }

  int a0 = 0, a1 = 8192, a2 = 16384;   // A buffer rotation (u16 offsets)

  // 16 MFMAs of one j-cluster: 8x hi then 8x lo (same-acc dep gap = 8)
#define CLUSTER(J, BH, BL)                                                     \
  {                                                                            \
    _Pragma("unroll")                                                          \
    for (int i = 0; i < 8; ++i)                                                \
      acc[i][J] = __builtin_amdgcn_mfma_f32_16x16x32_f16(aF[i], BH, acc[i][J], 0, 0, 0); \
    _Pragma("unroll")                                                          \
    for (int i = 0; i < 8; ++i)                                                \
      acc[i][J] = __builtin_amdgcn_mfma_f32_16x16x32_f16(aF[i], BL, acc[i][J], 0, 0, 0); \
  }

#pragma unroll 1
  for (int kt = 0; kt < 32; ++kt) {
    int curB = (kt & 1) * 4096, nxtB = 4096 - curB;
    if (kt < 31) {                      // B(kt+1) -> buf^1
      size_t ko = (size_t)(kt + 1) * 32;
      glds16(Bh0 + ko, &BhS[nxtB + bws0]);
      glds16(Bh1 + ko, &BhS[nxtB + bws1]);
      glds16(Bl0 + ko, &BlS[nxtB + bws0]);
      glds16(Bl1 + ko, &BlS[nxtB + bws1]);
    }
    if (kt < 30) {                      // A(kt+2) -> a2 (2-deep prefetch)
      size_t ka = (size_t)(kt + 2) * 32;
      glds16(A0 + ka, &Ah[a2 + aws0]);
      glds16(A1 + ka, &Ah[a2 + aws1]);
      glds16(A2 + ka, &Ah[a2 + aws2]);
      glds16(A3 + ka, &Ah[a2 + aws3]);
    }

    f16x8 aF[8];
#pragma unroll
    for (int i = 0; i < 8; ++i)
      aF[i] = *(const f16x8*)&Ah[a0 + (wm + i * 16 + c) * 32 + fch];

    // software-pipelined clusters: read j+1's B frags BETWEEN clusters so
    // cluster j's MFMAs overlap the next reads (fine-grained lgkmcnt).
    f16x8 bH0v = *(const f16x8*)&BhS[curB + (wn + 0 * 16 + c) * 32 + fch];
    f16x8 bL0v = *(const f16x8*)&BlS[curB + (wn + 0 * 16 + c) * 32 + fch];
    f16x8 bH1v = *(const f16x8*)&BhS[curB + (wn + 1 * 16 + c) * 32 + fch];
    f16x8 bL1v = *(const f16x8*)&BlS[curB + (wn + 1 * 16 + c) * 32 + fch];
    __builtin_amdgcn_s_setprio(1);
    CLUSTER(0, bH0v, bL0v)
    f16x8 bH2v = *(const f16x8*)&BhS[curB + (wn + 2 * 16 + c) * 32 + fch];
    f16x8 bL2v = *(const f16x8*)&BlS[curB + (wn + 2 * 16 + c) * 32 + fch];
    CLUSTER(1, bH1v, bL1v)
    f16x8 bH3v = *(const f16x8*)&BhS[curB + (wn + 3 * 16 + c) * 32 + fch];
    f16x8 bL3v = *(const f16x8*)&BlS[curB + (wn + 3 * 16 + c) * 32 + fch];
    CLUSTER(2, bH2v, bL2v)
    CLUSTER(3, bH3v, bL3v)
    __builtin_amdgcn_s_setprio(0);

    // counted wait: A(kt+1)+B(kt+1) landed, A(kt+2) stays in flight across barrier
    if (kt < 30) asm volatile("s_waitcnt vmcnt(4)" ::: "memory");
    else         asm volatile("s_waitcnt vmcnt(0)" ::: "memory");
    __builtin_amdgcn_s_barrier();
    __builtin_amdgcn_sched_barrier(0);
    int tmp = a0; a0 = a1; a1 = a2; a2 = tmp;
  }
#undef CLUSTER

  // epilogue: z -> tanh -> store bf16 ht; fused score partial (ctx dot)
  int bidx = m0 >> 11;                   // T = 2048; 256-row tile stays in one batch
  float ctxv[4], biasv[4];
#pragma unroll
  for (int j = 0; j < 4; ++j) {
    int col = n0 + wn + j * 16 + c;
    ctxv[j]  = ctx[bidx * Ee + col];
    biasv[j] = bias[col];
  }
#pragma unroll
  for (int i = 0; i < 8; ++i) {
#pragma unroll
    for (int r = 0; r < 4; ++r) {
      int rowG = m0 + wm + i * 16 + q * 4 + r;   // C/D: row=(lane>>4)*4+reg, col=lane&15
      u16* hrow = ht + (size_t)rowG * Ee + n0 + wn + c;
      float s = 0.f;
#pragma unroll
      for (int j = 0; j < 4; ++j) {
        float h = tanh_fast(acc[i][j][r] + biasv[j]);
        __hip_bfloat16 hb = __float2bfloat16(h);
        hrow[j * 16] = *(u16*)&hb;
        s += h * ctxv[j];
      }
      s += __shfl_xor(s, 1); s += __shfl_xor(s, 2);
      s += __shfl_xor(s, 4); s += __shfl_xor(s, 8);
      if (c == 0) atomicAdd(&scores[rowG], s);
    }
  }
}

// ---------------- K1 (fallback, verbatim round-2 378µs kernel): used if ws too small ----------------
__global__ __launch_bounds__(256, 2) void gemm_tanh_score_f32(
    const float* __restrict__ enc, const float* __restrict__ ctx,
    const float* __restrict__ bias,
    const u16* __restrict__ Wt_hi, const u16* __restrict__ Wt_lo,
    u16* __restrict__ ht, float* __restrict__ scores) {
  __shared__ __align__(16) u16 Ah [2*8192];
  __shared__ __align__(16) u16 BhS[2*4096];
  __shared__ __align__(16) u16 BlS[2*4096];

  int bx = blockIdx.x;
  int xcd = bx & 7, lb = bx >> 3;
  int nt = lb & 7, mtl = lb >> 3;
  int mt = xcd * 32 + mtl;
  int m0 = mt * 256, n0 = nt * 128;

  int tid = threadIdx.x;
  int w = tid >> 6, lane = tid & 63;
  int wm = (w & 1) * 128, wn = (w >> 1) * 64;
  int q = lane >> 4, c = lane & 15;
  int fch = (q ^ ((c >> 1) & 3)) * 8;

  f32x4 zero = {0.f, 0.f, 0.f, 0.f};
  f32x4 acc[8][4];
#pragma unroll
  for (int i = 0; i < 8; ++i)
#pragma unroll
    for (int j = 0; j < 4; ++j) acc[i][j] = zero;

  int arow = tid >> 3, ac8 = tid & 7;
  const float4* Abase = (const float4*)enc + ((size_t)(m0 + arow) * Ee >> 2) + ac8;
  int awbase = arow * 32 + (((ac8 >> 1) ^ ((arow >> 1) & 3)) << 3) + (ac8 & 1) * 4;

  int cidx0 = w * 2, cidx1 = w * 2 + 1;
  int r0 = cidx0 * 16 + (lane >> 2);
  int r1 = cidx1 * 16 + (lane >> 2);
  int lg0 = ((lane & 3) ^ ((r0 >> 1) & 3)) * 8;
  int lg1 = ((lane & 3) ^ ((r1 >> 1) & 3)) * 8;
  const u16* Bh0 = Wt_hi + (size_t)(n0 + r0) * Ee + lg0;
  const u16* Bh1 = Wt_hi + (size_t)(n0 + r1) * Ee + lg1;
  const u16* Bl0 = Wt_lo + (size_t)(n0 + r0) * Ee + lg0;
  const u16* Bl1 = Wt_lo + (size_t)(n0 + r1) * Ee + lg1;
  int bws0 = cidx0 * 512, bws1 = cidx1 * 512;

  {
    glds16(Bh0, &BhS[bws0]);
    glds16(Bh1, &BhS[bws1]);
    glds16(Bl0, &BlS[bws0]);
    glds16(Bl1, &BlS[bws1]);
    float4 f0 = Abase[0], f1 = Abase[(size_t)32 * (Ee/4)],
           f2 = Abase[(size_t)64 * (Ee/4)], f3 = Abase[(size_t)96 * (Ee/4)];
    float4 f4 = Abase[(size_t)128 * (Ee/4)], f5 = Abase[(size_t)160 * (Ee/4)],
           f6 = Abase[(size_t)192 * (Ee/4)], f7 = Abase[(size_t)224 * (Ee/4)];
    *(uint2*)&Ah[awbase + 0]    = make_uint2(pack2h(f0.x,f0.y), pack2h(f0.z,f0.w));
    *(uint2*)&Ah[awbase + 1024] = make_uint2(pack2h(f1.x,f1.y), pack2h(f1.z,f1.w));
    *(uint2*)&Ah[awbase + 2048] = make_uint2(pack2h(f2.x,f2.y), pack2h(f2.z,f2.w));
    *(uint2*)&Ah[awbase + 3072] = make_uint2(pack2h(f3.x,f3.y), pack2h(f3.z,f3.w));
    *(uint2*)&Ah[awbase + 4096] = make_uint2(pack2h(f4.x,f4.y), pack2h(f4.z,f4.w));
    *(uint2*)&Ah[awbase + 5120] = make_uint2(pack2h(f5.x,f5.y), pack2h(f5.z,f5.w));
    *(uint2*)&Ah[awbase + 6144] = make_uint2(pack2h(f6.x,f6.y), pack2h(f6.z,f6.w));
    *(uint2*)&Ah[awbase + 7168] = make_uint2(pack2h(f7.x,f7.y), pack2h(f7.z,f7.w));
    __syncthreads();
  }

#pragma unroll 2
  for (int kt = 0; kt < 32; ++kt) {
    int curA = (kt & 1) * 8192, nxtA = 8192 - curA;
    int curB = (kt & 1) * 4096, nxtB = 4096 - curB;
    float4 av[8];
    if (kt < 31) {
#pragma unroll
      for (int p = 0; p < 8; ++p)
        av[p] = Abase[(size_t)(32 * p) * (Ee / 4) + (size_t)(kt + 1) * 8];
      size_t ko = (size_t)(kt + 1) * 32;
      glds16(Bh0 + ko, &BhS[nxtB + bws0]);
      glds16(Bh1 + ko, &BhS[nxtB + bws1]);
      glds16(Bl0 + ko, &BlS[nxtB + bws0]);
      glds16(Bl1 + ko, &BlS[nxtB + bws1]);
    }

    f16x8 aF[8];
#pragma unroll
    for (int i = 0; i < 8; ++i)
      aF[i] = *(const f16x8*)&Ah[curA + (wm + i * 16 + c) * 32 + fch];

    __builtin_amdgcn_s_setprio(1);
#pragma unroll
    for (int j = 0; j < 4; ++j) {
      f16x8 bH = *(const f16x8*)&BhS[curB + (wn + j * 16 + c) * 32 + fch];
      f16x8 bL = *(const f16x8*)&BlS[curB + (wn + j * 16 + c) * 32 + fch];
#pragma unroll
      for (int i = 0; i < 8; ++i) {
        acc[i][j] = __builtin_amdgcn_mfma_f32_16x16x32_f16(aF[i], bH, acc[i][j], 0, 0, 0);
        acc[i][j] = __builtin_amdgcn_mfma_f32_16x16x32_f16(aF[i], bL, acc[i][j], 0, 0, 0);
      }
    }
    __builtin_amdgcn_s_setprio(0);

    if (kt < 31) {
#pragma unroll
      for (int p = 0; p < 8; ++p)
        *(uint2*)&Ah[nxtA + awbase + 1024 * p] =
            make_uint2(pack2h(av[p].x, av[p].y), pack2h(av[p].z, av[p].w));
    }
    __syncthreads();
  }

  int bidx = m0 >> 11;
  float ctxv[4], biasv[4];
#pragma unroll
  for (int j = 0; j < 4; ++j) {
    int col = n0 + wn + j * 16 + c;
    ctxv[j]  = ctx[bidx * Ee + col];
    biasv[j] = bias[col];
  }
#pragma unroll
  for (int i = 0; i < 8; ++i) {
#pragma unroll
    for (int r = 0; r < 4; ++r) {
      int rowG = m0 + wm + i * 16 + q * 4 + r;
      u16* hrow = ht + (size_t)rowG * Ee + n0 + wn + c;
      float s = 0.f;
#pragma unroll
      for (int j = 0; j < 4; ++j) {
        float h = tanh_fast(acc[i][j][r] + biasv[j]);
        __hip_bfloat16 hb = __float2bfloat16(h);
        hrow[j * 16] = *(u16*)&hb;
        s += h * ctxv[j];
      }
      s += __shfl_xor(s, 1); s += __shfl_xor(s, 2);
      s += __shfl_xor(s, 4); s += __shfl_xor(s, 8);
      if (c == 0) atomicAdd(&scores[rowG], s);
    }
  }
}

// ---------------- K2: softmax over T per batch row ----------------
__global__ __launch_bounds__(256) void softmax_t(const float* __restrict__ scores,
                                                 float* __restrict__ at) {
  __shared__ float red[256];
  int b = blockIdx.x, tid = threadIdx.x;
  float v[8];
  float mx = -3.0e38f;
#pragma unroll
  for (int i = 0; i < 8; ++i) {
    v[i] = scores[b * Tt + i * 256 + tid];
    mx = fmaxf(mx, v[i]);
  }
  red[tid] = mx; __syncthreads();
  for (int s = 128; s > 0; s >>= 1) {
    if (tid < s) red[tid] = fmaxf(red[tid], red[tid + s]);
    __syncthreads();
  }
  mx = red[0]; __syncthreads();
  float sum = 0.f;
#pragma unroll
  for (int i = 0; i < 8; ++i) { v[i] = __expf(v[i] - mx); sum += v[i]; }
  red[tid] = sum; __syncthreads();
  for (int s = 128; s > 0; s >>= 1) {
    if (tid < s) red[tid] += red[tid + s];
    __syncthreads();
  }
  float inv = 1.0f / red[0];
#pragma unroll
  for (int i = 0; i < 8; ++i) at[b * Tt + i * 256 + tid] = v[i] * inv;
}

// ---------------- K3: partial[b,tc,e] = sum_{t in chunk} at[b,t] * ht[b,t,e] ----------------
__global__ __launch_bounds__(256) void weighted_sum(const u16* __restrict__ ht,
                                                    const float* __restrict__ at,
                                                    float* __restrict__ part) {
  __shared__ float ats[64];
  int bx = blockIdx.x;
  int b = bx >> 5, tc = bx & 31;
  int tid = threadIdx.x;
  if (tid < 64) ats[tid] = at[b * Tt + tc * 64 + tid];
  __syncthreads();
  int e0 = tid * 4;
  const u16* base = ht + (size_t)(b * Tt + tc * 64) * Ee + e0;
  float s0 = 0.f, s1 = 0.f, s2 = 0.f, s3 = 0.f;
#pragma unroll 4
  for (int t = 0; t < 64; ++t) {
    float a = ats[t];
    uint2 u = *(const uint2*)(base + (size_t)t * Ee);
    s0 += a * __uint_as_float(u.x << 16);
    s1 += a * __uint_as_float(u.x & 0xffff0000u);
    s2 += a * __uint_as_float(u.y << 16);
    s3 += a * __uint_as_float(u.y & 0xffff0000u);
  }
  float4 out4 = make_float4(s0, s1, s2, s3);
  *(float4*)(part + ((size_t)(b * 32 + tc) * Ee + e0)) = out4;
}

// ---------------- K4: out[b,e] = sum_tc part[b,tc,e] ----------------
__global__ __launch_bounds__(256) void reduce_part(const float* __restrict__ part,
                                                   float* __restrict__ out) {
  int b = blockIdx.x, tid = threadIdx.x;
  float4 s = make_float4(0.f, 0.f, 0.f, 0.f);
#pragma unroll
  for (int tc = 0; tc < 32; ++tc) {
    float4 p = ((const float4*)(part + (size_t)(b * 32 + tc) * Ee))[tid];
    s.x += p.x; s.y += p.y; s.z += p.z; s.w += p.w;
  }
  ((float4*)(out + (size_t)b * Ee))[tid] = s;
}

extern "C" void kernel_launch(void* const* d_in, const int* in_sizes, int n_in,
                              void* d_out, int out_size, void* d_ws, size_t ws_size,
                              hipStream_t stream) {
  const float* enc  = (const float*)d_in[0];
  const float* ctx  = (const float*)d_in[1];
  const float* W    = (const float*)d_in[2];
  const float* bias = (const float*)d_in[3];
  float* out = (float*)d_out;

  char* ws = (char*)d_ws;
  u16* Wt_hi = (u16*)(ws);
  u16* Wt_lo = (u16*)(ws + (size_t)2 * 1024 * 1024);
  u16* ht    = (u16*)(ws + (size_t)4 * 1024 * 1024);
  float* scores = (float*)(ws + (size_t)4 * 1024 * 1024 + (size_t)Mm * Ee * 2);
  float* at     = scores + Mm;
  u16* enc16 = (u16*)(ws + (size_t)4 * 1024 * 1024 + (size_t)Mm * Ee * 2
                         + (size_t)Mm * 8);
  // part reuses the Wt region (dead after the GEMM): 32*32*1024 fp32 = 4 MB
  float* part = (float*)ws;

  size_t need = (size_t)4 * 1024 * 1024 + (size_t)Mm * Ee * 2 + (size_t)Mm * 8
              + (size_t)Mm * Ee * 2;   // Wt + ht + scores/at + enc16 ≈ 261 MB

  hipMemsetAsync(scores, 0, (size_t)Mm * sizeof(float), stream);
  wt_convert<<<dim3(32, 32), dim3(32, 8), 0, stream>>>(W, Wt_hi, Wt_lo);

  if (ws_size >= need) {
    enc_convert<<<dim3(8192), dim3(256), 0, stream>>>(enc, enc16);
    gemm_tanh_score16<<<dim3(2048), dim3(256), 0, stream>>>(enc16, ctx, bias,
                                                            Wt_hi, Wt_lo, ht, scores);
  } else {
    gemm_tanh_score_f32<<<dim3(2048), dim3(256), 0, stream>>>(enc, ctx, bias,
                                                              Wt_hi, Wt_lo, ht, scores);
  }
  softmax_t<<<dim3(32), dim3(256), 0, stream>>>(scores, at);
  weighted_sum<<<dim3(1024), dim3(256), 0, stream>>>(ht, at, part);
  reduce_part<<<dim3(32), dim3(256), 0, stream>>>(part, out);
}